// Round 6
// baseline (474.187 us; speedup 1.0000x reference)
//
#include <hip/hip_runtime.h>

#define NN 2048
#define NE 8192
#define ED 10
#define EH 32
#define HID 160
#define KT 5440          // 160*34 : k = i*34+q ; q<32: w2, q=32: b2, q=33: root
#define KS 10            // split-K: 10 slices of 544 (= 16 i's, 17 mfma steps)
#define KSL 544
#define MT 32            // nodes per block tile
#define APAD 552         // A-tile row stride (544+8), 16B-aligned rows
#define NNH (NN * HID)   // 327680

typedef __attribute__((ext_vector_type(8))) short short8;
typedef __attribute__((ext_vector_type(4))) float f32x4;
typedef unsigned int u32;

__device__ __forceinline__ ushort f2bf(float v) {   // RNE
    u32 u = __float_as_uint(v);
    u += 0x7FFF + ((u >> 16) & 1);
    return (ushort)(u >> 16);
}
__device__ __forceinline__ u32 packbf(float lo, float hi) {
    return ((u32)f2bf(hi) << 16) | f2bf(lo);
}

// ====== prep: edge MLP (2 sets), WcatT build, CSR (+cnt zero) ======
// blocks [0,512): MLP; [512,672): WcatT; 672: CSR
__global__ __launch_bounds__(256) void k_prep(
        const float* __restrict__ ea,
        const float* __restrict__ w1a, const float* __restrict__ b1a,
        const float* __restrict__ w1b, const float* __restrict__ b1b,
        float* __restrict__ ha, float* __restrict__ hb,
        const float* __restrict__ w2a, const float* __restrict__ b2a,
        const float* __restrict__ roota,
        const float* __restrict__ w2b, const float* __restrict__ b2b,
        const float* __restrict__ rootb,
        ushort* __restrict__ WcA, ushort* __restrict__ WcB,
        const int* __restrict__ ei, int* __restrict__ doff,
        int* __restrict__ degg, float* __restrict__ dinv,
        int2* __restrict__ delist2, int* __restrict__ cnt) {
    __shared__ __align__(16) char smem[21760];
    int b = blockIdx.x, t = threadIdx.x;

    if (b < 512) {                       // ---- h = relu(ea@w1+b1), 4 elems/thread
        int set = b >> 8, rel = b & 255;
        const float* w1 = set ? w1b : w1a;
        const float* b1 = set ? b1b : b1a;
        float* h = set ? hb : ha;
        int idx = rel * 1024 + t * 4;
        int e = idx >> 5, j0 = idx & 31;
        float o4[4];
#pragma unroll
        for (int u = 0; u < 4; ++u) {
            float acc = b1[j0 + u];
#pragma unroll
            for (int i = 0; i < ED; ++i) acc += ea[e * ED + i] * w1[i * EH + j0 + u];
            o4[u] = fmaxf(acc, 0.f);
        }
        *(float4*)&h[idx] = *(const float4*)o4;
        return;
    }
    if (b < 672) {                       // ---- WcatT[o][i*34+q] bf16, LDS-coalesced
        int rel = b - 512;               // 0..159
        int set = rel / 80, i0 = (rel % 80) * 2;
        u32 (*tile)[34] = (u32(*)[34])smem;   // [160 o][34 u32]
        const float* w2 = set ? w2b : w2a;
        const float* b2 = set ? b2b : b2a;
        const float* root = set ? rootb : roota;
        ushort* W = set ? WcB : WcA;
        if (t < HID) {
#pragma unroll
            for (int di = 0; di < 2; ++di) {
                int i = i0 + di;
#pragma unroll
                for (int p = 0; p < 16; ++p) {
                    float v0 = w2[(size_t)(2 * p) * 25600 + i * HID + t];
                    float v1 = w2[(size_t)(2 * p + 1) * 25600 + i * HID + t];
                    tile[t][di * 17 + p] = packbf(v0, v1);
                }
                tile[t][di * 17 + 16] = packbf(b2[i * HID + t], root[i * HID + t]);
            }
        }
        __syncthreads();
        u32* dst = (u32*)W;
        for (int w = t; w < 5440; w += 256) {   // coalesced: 34 consecutive u32/row
            int o = w / 34, j = w - o * 34;
            dst[(size_t)o * 2720 + i0 * 17 + j] = tile[o][j];
        }
        return;
    }
    // ---- CSR build over dst (single block, 256 threads) ----
    if (t < 64) cnt[t] = 0;
    int* deg = (int*)smem;               // NN
    int* cur = deg + NN;                 // NN
    int* part = cur + NN;                // 256
    for (int i = t; i < NN; i += 256) deg[i] = 0;
    __syncthreads();
    for (int e = t; e < NE; e += 256) atomicAdd(&deg[ei[NE + e]], 1);
    __syncthreads();
    int loc[8], s = 0;
#pragma unroll
    for (int i = 0; i < 8; ++i) { loc[i] = s; s += deg[t * 8 + i]; }
    part[t] = s;
    __syncthreads();
    int tot = s;
    for (int st = 1; st < 256; st <<= 1) {
        int v = (t >= st) ? part[t - st] : 0;
        __syncthreads();
        part[t] += v;
        __syncthreads();
    }
    int base = part[t] - tot;
#pragma unroll
    for (int i = 0; i < 8; ++i) {
        int d = t * 8 + i;
        doff[d] = base + loc[i];
        cur[d] = base + loc[i];
        degg[d] = deg[d];
        dinv[d] = 1.0f / fmaxf((float)deg[d], 1.0f);
    }
    __syncthreads();
    for (int e = t; e < NE; e += 256) {
        int d = ei[NE + e];
        int src = ei[e];
        int p = atomicAdd(&cur[d], 1);
        delist2[p] = make_int2(e, src);
    }
}

// ======= fused layer: A-tile in LDS, barrier-free MFMA K-loop (B from L2), =======
// ======= Cp slice store, last-block-per-bm reduces + bias (+relu) to xout. =======
// grid (64 bm, 10 ks), 256 threads, 4 blocks/CU.
__global__ __launch_bounds__(256, 4) void k_layer(
        const float* __restrict__ xin,
        const float* __restrict__ h, const ushort* __restrict__ wc,
        const int2* __restrict__ delist2, const int* __restrict__ doff,
        const int* __restrict__ degg, const float* __restrict__ dinv,
        float* __restrict__ Cp, int* __restrict__ cnt,
        const float* __restrict__ bias, float* __restrict__ xout, int dorelu) {
    __shared__ __align__(16) ushort sA[MT * APAD];        // 35328 B
    __shared__ int s_old;
    int t = threadIdx.x;
    int bm = blockIdx.x, ks = blockIdx.y;
    int d0 = bm * MT, i0 = ks * 16;

    // ---------- phase A: per-cell (d, i) accumulation, direct L2 reads ----------
    int il = t & 15, i = i0 + il;
    int dA = d0 + (t >> 4), dB = dA + 16;
    float accA[33], accB[33];
#pragma unroll
    for (int q = 0; q < 33; ++q) { accA[q] = 0.f; accB[q] = 0.f; }

    int aLo = doff[dA], aHi = aLo + degg[dA];
    for (int o = aLo; o < aHi; ++o) {
        int2 es = delist2[o];            // (e, src)
        float xs = xin[es.y * HID + i];
        const float4* hp = (const float4*)&h[(size_t)es.x * EH];
#pragma unroll
        for (int q8 = 0; q8 < 8; ++q8) {
            float4 hv = hp[q8];
            accA[q8 * 4 + 0] += hv.x * xs;
            accA[q8 * 4 + 1] += hv.y * xs;
            accA[q8 * 4 + 2] += hv.z * xs;
            accA[q8 * 4 + 3] += hv.w * xs;
        }
        accA[32] += xs;
    }
    int bLo = doff[dB], bHi = bLo + degg[dB];
    for (int o = bLo; o < bHi; ++o) {
        int2 es = delist2[o];
        float xs = xin[es.y * HID + i];
        const float4* hp = (const float4*)&h[(size_t)es.x * EH];
#pragma unroll
        for (int q8 = 0; q8 < 8; ++q8) {
            float4 hv = hp[q8];
            accB[q8 * 4 + 0] += hv.x * xs;
            accB[q8 * 4 + 1] += hv.y * xs;
            accB[q8 * 4 + 2] += hv.z * xs;
            accB[q8 * 4 + 3] += hv.w * xs;
        }
        accB[32] += xs;
    }
    float rootA = xin[dA * HID + i], rootB = xin[dB * HID + i];

    {
        float diA = dinv[dA], diB = dinv[dB];
        u32* pa = (u32*)&sA[(t >> 4) * APAD + il * 34];
        u32* pb = (u32*)&sA[((t >> 4) + 16) * APAD + il * 34];
#pragma unroll
        for (int p = 0; p < 16; ++p) {
            pa[p] = packbf(accA[2 * p] * diA, accA[2 * p + 1] * diA);
            pb[p] = packbf(accB[2 * p] * diB, accB[2 * p + 1] * diB);
        }
        pa[16] = packbf(accA[32] * diA, rootA);
        pb[16] = packbf(accB[32] * diB, rootB);
    }
    __syncthreads();   // A-tile visible; only barrier in the kernel body

    // ---------- phase B: 17-step K-loop, B straight from global (L2-hot) ----------
    int wid = t >> 6, lane = t & 63;
    int wm = (wid >> 1) * 16, wn = (wid & 1) * 80;
    int lr = lane & 15, lk = lane >> 4;
    f32x4 acc[5];
#pragma unroll
    for (int j = 0; j < 5; ++j) acc[j] = (f32x4){0.f, 0.f, 0.f, 0.f};

    const ushort* wb = wc + (size_t)ks * KSL + lk * 8;
#pragma unroll
    for (int c = 0; c < 17; ++c) {
        short8 av = *(const short8*)&sA[(wm + lr) * APAD + c * 32 + lk * 8];
        short8 bv[5];
#pragma unroll
        for (int nt = 0; nt < 5; ++nt) {
            int row = wn + nt * 16 + lr;
            bv[nt] = *(const short8*)&wb[(size_t)row * KT + c * 32];
        }
#pragma unroll
        for (int nt = 0; nt < 5; ++nt)
            acc[nt] = __builtin_amdgcn_mfma_f32_16x16x32_bf16(av, bv[nt], acc[nt], 0, 0, 0);
    }

    // ---------- store Cp slice (plain coalesced stores) ----------
    float* Cb = Cp + (size_t)ks * NNH;
#pragma unroll
    for (int nt = 0; nt < 5; ++nt) {
        int n = wn + nt * 16 + lr;
        int m0 = d0 + wm + lk * 4;
#pragma unroll
        for (int r = 0; r < 4; ++r)
            Cb[(size_t)(m0 + r) * HID + n] = acc[nt][r];
    }

    // ---------- last block for this bm reduces the 10 slices ----------
    __threadfence();                      // release our Cp stores (agent scope)
    __syncthreads();
    if (t == 0) s_old = atomicAdd(&cnt[bm], 1);
    __syncthreads();
    if (s_old == KS - 1) {
        __threadfence();                  // acquire: invalidate caches before reads
#pragma unroll
        for (int j = 0; j < 5; ++j) {
            int f4 = j * 256 + t;         // 0..1279 float4s of this bm's 32 nodes
            int node = d0 + f4 / 40;
            int o = (f4 % 40) * 4;
            float4 s = *(const float4*)&bias[o];
#pragma unroll
            for (int p = 0; p < KS; ++p) {
                float4 v = *(const float4*)&Cp[(size_t)p * NNH + node * HID + o];
                s.x += v.x; s.y += v.y; s.z += v.z; s.w += v.w;
            }
            if (dorelu) {
                s.x = fmaxf(s.x, 0.f); s.y = fmaxf(s.y, 0.f);
                s.z = fmaxf(s.z, 0.f); s.w = fmaxf(s.w, 0.f);
            }
            *(float4*)&xout[node * HID + o] = s;
        }
        if (t == 0) cnt[bm] = 0;          // ready for next dispatch
    }
}

extern "C" void kernel_launch(void* const* d_in, const int* in_sizes, int n_in,
                              void* d_out, int out_size, void* d_ws, size_t ws_size,
                              hipStream_t stream) {
    const float* x     = (const float*)d_in[0];
    const float* ea    = (const float*)d_in[1];
    const float* w1a   = (const float*)d_in[2];
    const float* b1a   = (const float*)d_in[3];
    const float* w2a   = (const float*)d_in[4];
    const float* b2a   = (const float*)d_in[5];
    const float* roota = (const float*)d_in[6];
    const float* biasa = (const float*)d_in[7];
    const float* w1b   = (const float*)d_in[8];
    const float* b1b   = (const float*)d_in[9];
    const float* w2b   = (const float*)d_in[10];
    const float* b2b   = (const float*)d_in[11];
    const float* rootb = (const float*)d_in[12];
    const float* biasb = (const float*)d_in[13];
    const int*   ei    = (const int*)d_in[14];
    float* out = (float*)d_out;

    char* p = (char*)d_ws;
    float* Cp    = (float*)p;  p += (size_t)KS * NNH * 4;   // 13.1 MB
    float* xacc0 = (float*)p;  p += (size_t)NNH * 4;        // 1.31 MB
    float* xacc1 = (float*)p;  p += (size_t)NNH * 4;
    ushort* WcA  = (ushort*)p; p += (size_t)HID * KT * 2;   // 1.74 MB
    ushort* WcB  = (ushort*)p; p += (size_t)HID * KT * 2;
    float* h_a   = (float*)p;  p += (size_t)NE * EH * 4;
    float* h_b   = (float*)p;  p += (size_t)NE * EH * 4;
    int* doff    = (int*)p;    p += NN * 4;
    int* degg    = (int*)p;    p += NN * 4;
    float* dinv  = (float*)p;  p += NN * 4;
    int2* delist2 = (int2*)p;  p += NE * 8;
    int* cnt     = (int*)p;    p += 64 * 4;

    k_prep<<<673, 256, 0, stream>>>(ea, w1a, b1a, w1b, b1b, h_a, h_b,
                                    w2a, b2a, roota, w2b, b2b, rootb, WcA, WcB,
                                    ei, doff, degg, dinv, delist2, cnt);

    dim3 lg(NN / MT, KS);
    // layer 0: reads x, winners write relu(biasa + sum) -> xacc0
    k_layer<<<lg, 256, 0, stream>>>(x, h_a, WcA, delist2, doff, degg, dinv,
                                    Cp, cnt, biasa, xacc0, 1);
    // layer 1: reads xacc0, winners write relu(biasb + sum) -> xacc1
    k_layer<<<lg, 256, 0, stream>>>(xacc0, h_b, WcB, delist2, doff, degg, dinv,
                                    Cp, cnt, biasb, xacc1, 1);
    // layer 2: reads xacc1, winners write biasb + sum -> out (no relu)
    k_layer<<<lg, 256, 0, stream>>>(xacc1, h_b, WcB, delist2, doff, degg, dinv,
                                    Cp, cnt, biasb, out, 0);
}

// Round 7
// 213.344 us; speedup vs baseline: 2.2226x; 2.2226x over previous
//
#include <hip/hip_runtime.h>

#define NN 2048
#define NE 8192
#define ED 10
#define EH 32
#define HID 160
#define KT 5440          // 160*34 : k = i*34+q ; q<32: w2, q=32: b2, q=33: root
#define KS 10            // split-K: 10 slices of 544 (= 16 i's, 17 mfma steps)
#define KSL 544
#define MT 32            // nodes per block tile
#define APAD 552         // A-tile row stride (544+8), 16B-aligned rows
#define NNH (NN * HID)   // 327680

typedef __attribute__((ext_vector_type(8))) short short8;
typedef __attribute__((ext_vector_type(4))) float f32x4;
typedef unsigned int u32;

__device__ __forceinline__ ushort f2bf(float v) {   // RNE
    u32 u = __float_as_uint(v);
    u += 0x7FFF + ((u >> 16) & 1);
    return (ushort)(u >> 16);
}
__device__ __forceinline__ u32 packbf(float lo, float hi) {
    return ((u32)f2bf(hi) << 16) | f2bf(lo);
}
__device__ __forceinline__ void gl2lds16(const ushort* g, ushort* l) {
    __builtin_amdgcn_global_load_lds(
        (const __attribute__((address_space(1))) u32*)g,
        (__attribute__((address_space(3))) u32*)l, 16, 0, 0);
}

// ====== prep (1024-thread blocks): edge MLP (2 sets), WcatT build, CSR ======
// blocks [0,128): MLP; [128,288): WcatT; 288: CSR
__global__ __launch_bounds__(1024) void k_prep(
        const float* __restrict__ ea,
        const float* __restrict__ w1a, const float* __restrict__ b1a,
        const float* __restrict__ w1b, const float* __restrict__ b1b,
        float* __restrict__ ha, float* __restrict__ hb,
        const float* __restrict__ w2a, const float* __restrict__ b2a,
        const float* __restrict__ roota,
        const float* __restrict__ w2b, const float* __restrict__ b2b,
        const float* __restrict__ rootb,
        ushort* __restrict__ WcA, ushort* __restrict__ WcB,
        const int* __restrict__ ei, int* __restrict__ doff,
        int* __restrict__ degg, float* __restrict__ dinv,
        int2* __restrict__ delist2) {
    __shared__ __align__(16) char smem[21760];
    int b = blockIdx.x, t = threadIdx.x;

    if (b < 128) {                       // ---- h = relu(ea@w1+b1), 4 elems/thread
        int set = b >> 6, rel = b & 63;
        const float* w1 = set ? w1b : w1a;
        const float* b1 = set ? b1b : b1a;
        float* h = set ? hb : ha;
        int idx = rel * 4096 + t * 4;
        int e = idx >> 5, j0 = idx & 31;
        float o4[4];
#pragma unroll
        for (int u = 0; u < 4; ++u) {
            float acc = b1[j0 + u];
#pragma unroll
            for (int i = 0; i < ED; ++i) acc += ea[e * ED + i] * w1[i * EH + j0 + u];
            o4[u] = fmaxf(acc, 0.f);
        }
        *(float4*)&h[idx] = *(const float4*)o4;
        return;
    }
    if (b < 288) {                       // ---- WcatT[o][i*34+q] bf16, LDS-coalesced
        int rel = b - 128;               // 0..159
        int set = rel / 80, i0 = (rel % 80) * 2;
        u32 (*tile)[34] = (u32(*)[34])smem;   // [160 o][34 u32]
        const float* w2 = set ? w2b : w2a;
        const float* b2 = set ? b2b : b2a;
        const float* root = set ? rootb : roota;
        ushort* W = set ? WcB : WcA;
        if (t < HID) {
#pragma unroll
            for (int di = 0; di < 2; ++di) {
                int i = i0 + di;
#pragma unroll
                for (int p = 0; p < 16; ++p) {
                    float v0 = w2[(size_t)(2 * p) * 25600 + i * HID + t];
                    float v1 = w2[(size_t)(2 * p + 1) * 25600 + i * HID + t];
                    tile[t][di * 17 + p] = packbf(v0, v1);
                }
                tile[t][di * 17 + 16] = packbf(b2[i * HID + t], root[i * HID + t]);
            }
        }
        __syncthreads();
        u32* dst = (u32*)W;
        for (int w = t; w < 5440; w += 1024) {  // coalesced: 34 consecutive u32/row
            int o = w / 34, j = w - o * 34;
            dst[(size_t)o * 2720 + i0 * 17 + j] = tile[o][j];
        }
        return;
    }
    // ---- CSR build over dst (single block, 1024 threads) ----
    int* deg = (int*)smem;               // NN
    int* cur = deg + NN;                 // NN
    int* part = cur + NN;                // 1024
    for (int i = t; i < NN; i += 1024) deg[i] = 0;
    __syncthreads();
    for (int e = t; e < NE; e += 1024) atomicAdd(&deg[ei[NE + e]], 1);
    __syncthreads();
    int loc[2], s = 0;
#pragma unroll
    for (int i = 0; i < 2; ++i) { loc[i] = s; s += deg[t * 2 + i]; }
    part[t] = s;
    __syncthreads();
    int tot = s;
    for (int st = 1; st < 1024; st <<= 1) {
        int v = (t >= st) ? part[t - st] : 0;
        __syncthreads();
        part[t] += v;
        __syncthreads();
    }
    int base = part[t] - tot;
#pragma unroll
    for (int i = 0; i < 2; ++i) {
        int d = t * 2 + i;
        doff[d] = base + loc[i];
        cur[d] = base + loc[i];
        degg[d] = deg[d];
        dinv[d] = 1.0f / fmaxf((float)deg[d], 1.0f);
    }
    __syncthreads();
    for (int e = t; e < NE; e += 1024) {
        int d = ei[NE + e];
        int src = ei[e];
        int p = atomicAdd(&cur[d], 1);
        delist2[p] = make_int2(e, src);
    }
}

// ======= fused layer: A-tile in LDS, double-buffered MFMA K-loop, Cp stores =======
// grid (64 bm, 10 ks), 256 threads.
__global__ __launch_bounds__(256) void k_layer(
        const float* __restrict__ xin,
        const float* __restrict__ h, const ushort* __restrict__ wc,
        const int2* __restrict__ delist2, const int* __restrict__ doff,
        const int* __restrict__ degg, const float* __restrict__ dinv,
        float* __restrict__ Cp) {
    __shared__ __align__(16) ushort sA[MT * APAD];        // 35328 B
    __shared__ __align__(16) ushort sB[2][160 * 32];      // 20480 B
    int t = threadIdx.x;
    int bm = blockIdx.x, ks = blockIdx.y;
    int d0 = bm * MT, i0 = ks * 16;

    // B-slice stage: linear LDS dest, XOR-swizzled global source (slot=lk^((row>>1)&3))
    auto stage = [&](int buf, int c) {
        size_t k0 = (size_t)ks * KSL + c * 32;
#pragma unroll
        for (int q = 0; q < 2; ++q) {
            int s = t + q * 256;
            int row = s >> 2;
            int lkq = (s & 3) ^ ((row >> 1) & 3);
            gl2lds16(&wc[(size_t)row * KT + k0 + lkq * 8], &sB[buf][s * 8]);
        }
        if (t < 128) {
            int s = t + 512;
            int row = s >> 2;
            int lkq = (s & 3) ^ ((row >> 1) & 3);
            gl2lds16(&wc[(size_t)row * KT + k0 + lkq * 8], &sB[buf][s * 8]);
        }
    };
    stage(0, 0);       // issued at entry; completes under phase A

    // ---------- phase A: per-cell (d, i) accumulation, direct L2 reads ----------
    int il = t & 15, i = i0 + il;
    int dA = d0 + (t >> 4), dB = dA + 16;
    float accA[33], accB[33];
#pragma unroll
    for (int q = 0; q < 33; ++q) { accA[q] = 0.f; accB[q] = 0.f; }

    int aLo = doff[dA], aHi = aLo + degg[dA];
    for (int o = aLo; o < aHi; ++o) {
        int2 es = delist2[o];            // (e, src)
        float xs = xin[es.y * HID + i];
        const float4* hp = (const float4*)&h[(size_t)es.x * EH];
#pragma unroll
        for (int q8 = 0; q8 < 8; ++q8) {
            float4 hv = hp[q8];
            accA[q8 * 4 + 0] += hv.x * xs;
            accA[q8 * 4 + 1] += hv.y * xs;
            accA[q8 * 4 + 2] += hv.z * xs;
            accA[q8 * 4 + 3] += hv.w * xs;
        }
        accA[32] += xs;
    }
    int bLo = doff[dB], bHi = bLo + degg[dB];
    for (int o = bLo; o < bHi; ++o) {
        int2 es = delist2[o];
        float xs = xin[es.y * HID + i];
        const float4* hp = (const float4*)&h[(size_t)es.x * EH];
#pragma unroll
        for (int q8 = 0; q8 < 8; ++q8) {
            float4 hv = hp[q8];
            accB[q8 * 4 + 0] += hv.x * xs;
            accB[q8 * 4 + 1] += hv.y * xs;
            accB[q8 * 4 + 2] += hv.z * xs;
            accB[q8 * 4 + 3] += hv.w * xs;
        }
        accB[32] += xs;
    }
    float rootA = xin[dA * HID + i], rootB = xin[dB * HID + i];

    {
        float diA = dinv[dA], diB = dinv[dB];
        u32* pa = (u32*)&sA[(t >> 4) * APAD + il * 34];
        u32* pb = (u32*)&sA[((t >> 4) + 16) * APAD + il * 34];
#pragma unroll
        for (int p = 0; p < 16; ++p) {
            pa[p] = packbf(accA[2 * p] * diA, accA[2 * p + 1] * diA);
            pb[p] = packbf(accB[2 * p] * diB, accB[2 * p + 1] * diB);
        }
        pa[16] = packbf(accA[32] * diA, rootA);
        pb[16] = packbf(accB[32] * diB, rootB);
    }
    __syncthreads();   // A-tile visible + sB[0] staged (barrier drains vmcnt)

    // ---------- phase B: 17-step double-buffered MFMA ----------
    int wid = t >> 6, lane = t & 63;
    int wm = (wid >> 1) * 16, wn = (wid & 1) * 80;
    int lr = lane & 15, lk = lane >> 4;
    f32x4 acc[5];
#pragma unroll
    for (int j = 0; j < 5; ++j) acc[j] = (f32x4){0.f, 0.f, 0.f, 0.f};

    for (int c = 0; c < 17; ++c) {
        int cur = c & 1;
        if (c + 1 < 17) stage(cur ^ 1, c + 1);   // prefetch hides under MFMA
        short8 av = *(const short8*)&sA[(wm + lr) * APAD + c * 32 + lk * 8];
        short8 bv[5];
#pragma unroll
        for (int nt = 0; nt < 5; ++nt) {
            int row = wn + nt * 16 + lr;
            bv[nt] = *(const short8*)&sB[cur][row * 32 +
                                             (lk ^ ((row >> 1) & 3)) * 8];
        }
#pragma unroll
        for (int nt = 0; nt < 5; ++nt)
            acc[nt] = __builtin_amdgcn_mfma_f32_16x16x32_bf16(av, bv[nt], acc[nt], 0, 0, 0);
        __syncthreads();
    }

    // ---------- epilogue: plain coalesced Cp slice stores ----------
    float* Cb = Cp + (size_t)ks * NNH;
#pragma unroll
    for (int nt = 0; nt < 5; ++nt) {
        int n = wn + nt * 16 + lr;
        int m0 = d0 + wm + lk * 4;
#pragma unroll
        for (int r = 0; r < 4; ++r)
            Cb[(size_t)(m0 + r) * HID + n] = acc[nt][r];
    }
}

// ====== fin: xout = [relu](bias + sum of Cp slices), 4 f32/thread ======
__global__ __launch_bounds__(256) void k_fin(const float* __restrict__ Cp,
                                             const float* __restrict__ bias,
                                             float* __restrict__ xout, int dorelu) {
    int base = (blockIdx.x * 256 + threadIdx.x) * 4;   // < 327680
    float4 s = *(const float4*)&bias[base % HID];
#pragma unroll
    for (int p = 0; p < KS; ++p) {
        float4 v = *(const float4*)&Cp[(size_t)p * NNH + base];
        s.x += v.x; s.y += v.y; s.z += v.z; s.w += v.w;
    }
    if (dorelu) {
        s.x = fmaxf(s.x, 0.f); s.y = fmaxf(s.y, 0.f);
        s.z = fmaxf(s.z, 0.f); s.w = fmaxf(s.w, 0.f);
    }
    *(float4*)&xout[base] = s;
}

extern "C" void kernel_launch(void* const* d_in, const int* in_sizes, int n_in,
                              void* d_out, int out_size, void* d_ws, size_t ws_size,
                              hipStream_t stream) {
    const float* x     = (const float*)d_in[0];
    const float* ea    = (const float*)d_in[1];
    const float* w1a   = (const float*)d_in[2];
    const float* b1a   = (const float*)d_in[3];
    const float* w2a   = (const float*)d_in[4];
    const float* b2a   = (const float*)d_in[5];
    const float* roota = (const float*)d_in[6];
    const float* biasa = (const float*)d_in[7];
    const float* w1b   = (const float*)d_in[8];
    const float* b1b   = (const float*)d_in[9];
    const float* w2b   = (const float*)d_in[10];
    const float* b2b   = (const float*)d_in[11];
    const float* rootb = (const float*)d_in[12];
    const float* biasb = (const float*)d_in[13];
    const int*   ei    = (const int*)d_in[14];
    float* out = (float*)d_out;

    char* p = (char*)d_ws;
    float* Cp    = (float*)p;  p += (size_t)KS * NNH * 4;   // 13.1 MB
    float* xacc0 = (float*)p;  p += (size_t)NNH * 4;        // 1.31 MB
    float* xacc1 = (float*)p;  p += (size_t)NNH * 4;
    ushort* WcA  = (ushort*)p; p += (size_t)HID * KT * 2;   // 1.74 MB
    ushort* WcB  = (ushort*)p; p += (size_t)HID * KT * 2;
    float* h_a   = (float*)p;  p += (size_t)NE * EH * 4;
    float* h_b   = (float*)p;  p += (size_t)NE * EH * 4;
    int* doff    = (int*)p;    p += NN * 4;
    int* degg    = (int*)p;    p += NN * 4;
    float* dinv  = (float*)p;  p += NN * 4;
    int2* delist2 = (int2*)p;  p += NE * 8;

    k_prep<<<289, 1024, 0, stream>>>(ea, w1a, b1a, w1b, b1b, h_a, h_b,
                                     w2a, b2a, roota, w2b, b2b, rootb, WcA, WcB,
                                     ei, doff, degg, dinv, delist2);

    dim3 lg(NN / MT, KS);
    // layer 0
    k_layer<<<lg, 256, 0, stream>>>(x, h_a, WcA, delist2, doff, degg, dinv, Cp);
    k_fin<<<NNH / 1024, 256, 0, stream>>>(Cp, biasa, xacc0, 1);
    // layer 1
    k_layer<<<lg, 256, 0, stream>>>(xacc0, h_b, WcB, delist2, doff, degg, dinv, Cp);
    k_fin<<<NNH / 1024, 256, 0, stream>>>(Cp, biasb, xacc1, 1);
    // layer 2
    k_layer<<<lg, 256, 0, stream>>>(xacc1, h_b, WcB, delist2, doff, degg, dinv, Cp);
    k_fin<<<NNH / 1024, 256, 0, stream>>>(Cp, biasb, out, 0);
}